// Round 1
// baseline (169.489 us; speedup 1.0000x reference)
//
#include <hip/hip_runtime.h>
#include <hip/hip_bf16.h>

#define GRID  1280
#define BLOCK 256
#define LOG_CLAMP -100.0f

struct Partials {
    double bce[GRID];
    double w1s[GRID];
    double w2s[GRID];
    unsigned int cnt[GRID];
};

__device__ __forceinline__ double wave_reduce_d(double v) {
#pragma unroll
    for (int o = 32; o > 0; o >>= 1) v += __shfl_down(v, o, 64);
    return v;
}
__device__ __forceinline__ unsigned int wave_reduce_u(unsigned int v) {
#pragma unroll
    for (int o = 32; o > 0; o >>= 1) v += __shfl_down(v, o, 64);
    return v;
}

__global__ __launch_bounds__(BLOCK) void reduce_kernel(
    const float* __restrict__ p, const float* __restrict__ y,
    const float* __restrict__ w1, const float* __restrict__ w2,
    int nB4, int n14, int n24, Partials* __restrict__ ws)
{
    const float4* __restrict__ p4  = (const float4*)p;
    const float4* __restrict__ y4  = (const float4*)y;
    const float4* __restrict__ w14 = (const float4*)w1;
    const float4* __restrict__ w24 = (const float4*)w2;

    const int tid    = blockIdx.x * BLOCK + threadIdx.x;
    const int stride = GRID * BLOCK;

    double bce = 0.0, s1 = 0.0, s2 = 0.0;
    unsigned int cnt = 0;

    // ---- BCE + accuracy over model_outputs / labels ----
    for (int i = tid; i < nB4; i += stride) {
        float4 pv = p4[i];
        float4 yv = y4[i];
        float bacc = 0.0f;
#define BCE_COMP(px, yx)                                                \
        {                                                               \
            float lp  = fmaxf(logf(px), LOG_CLAMP);                     \
            float l1  = fmaxf(log1pf(-(px)), LOG_CLAMP);                \
            bacc += (yx) * lp + (1.0f - (yx)) * l1;                     \
            cnt  += (fabsf((px) - (yx)) < 0.5f) ? 1u : 0u;              \
        }
        BCE_COMP(pv.x, yv.x)
        BCE_COMP(pv.y, yv.y)
        BCE_COMP(pv.z, yv.z)
        BCE_COMP(pv.w, yv.w)
#undef BCE_COMP
        bce += (double)bacc;
    }

    // ---- sum of squares, w1 ----
    for (int i = tid; i < n14; i += stride) {
        float4 v = w14[i];
        float q = v.x * v.x + v.y * v.y + v.z * v.z + v.w * v.w;
        s1 += (double)q;
    }

    // ---- sum of squares, w2 ----
    for (int i = tid; i < n24; i += stride) {
        float4 v = w24[i];
        float q = v.x * v.x + v.y * v.y + v.z * v.z + v.w * v.w;
        s2 += (double)q;
    }

    // ---- block reduction: wave shuffle then LDS across 4 waves ----
    double rb = wave_reduce_d(bce);
    double r1 = wave_reduce_d(s1);
    double r2 = wave_reduce_d(s2);
    unsigned int rc = wave_reduce_u(cnt);

    __shared__ double sb[BLOCK / 64], s1s[BLOCK / 64], s2s[BLOCK / 64];
    __shared__ unsigned int scs[BLOCK / 64];
    const int wave = threadIdx.x >> 6;
    const int lane = threadIdx.x & 63;
    if (lane == 0) { sb[wave] = rb; s1s[wave] = r1; s2s[wave] = r2; scs[wave] = rc; }
    __syncthreads();
    if (threadIdx.x == 0) {
        double tb = 0.0, t1 = 0.0, t2 = 0.0;
        unsigned int tc = 0;
#pragma unroll
        for (int w = 0; w < BLOCK / 64; ++w) { tb += sb[w]; t1 += s1s[w]; t2 += s2s[w]; tc += scs[w]; }
        ws->bce[blockIdx.x] = tb;
        ws->w1s[blockIdx.x] = t1;
        ws->w2s[blockIdx.x] = t2;
        ws->cnt[blockIdx.x] = tc;
    }
}

__global__ __launch_bounds__(BLOCK) void finalize_kernel(
    const Partials* __restrict__ ws, float* __restrict__ out, int nB)
{
    double bce = 0.0, s1 = 0.0, s2 = 0.0;
    unsigned int cnt = 0;
    for (int i = threadIdx.x; i < GRID; i += BLOCK) {
        bce += ws->bce[i];
        s1  += ws->w1s[i];
        s2  += ws->w2s[i];
        cnt += ws->cnt[i];
    }
    double rb = wave_reduce_d(bce);
    double r1 = wave_reduce_d(s1);
    double r2 = wave_reduce_d(s2);
    unsigned int rc = wave_reduce_u(cnt);

    __shared__ double sb[BLOCK / 64], s1s[BLOCK / 64], s2s[BLOCK / 64];
    __shared__ unsigned int scs[BLOCK / 64];
    const int wave = threadIdx.x >> 6;
    const int lane = threadIdx.x & 63;
    if (lane == 0) { sb[wave] = rb; s1s[wave] = r1; s2s[wave] = r2; scs[wave] = rc; }
    __syncthreads();
    if (threadIdx.x == 0) {
        double tb = 0.0, t1 = 0.0, t2 = 0.0;
        unsigned int tc = 0;
#pragma unroll
        for (int w = 0; w < BLOCK / 64; ++w) { tb += sb[w]; t1 += s1s[w]; t2 += s2s[w]; tc += scs[w]; }
        const double invB = 1.0 / (double)nB;
        // cross_loss = -mean(y*log_p + (1-y)*log_1mp); tb holds the (signed) sum
        double result = -tb * invB + (0.01 * t1 + 0.001 * t2) * (0.5 * invB);
        out[0] = (float)result;
        out[1] = (float)tc;
    }
}

extern "C" void kernel_launch(void* const* d_in, const int* in_sizes, int n_in,
                              void* d_out, int out_size, void* d_ws, size_t ws_size,
                              hipStream_t stream) {
    const float* p  = (const float*)d_in[0];   // model_outputs
    const float* y  = (const float*)d_in[1];   // labels
    const float* w1 = (const float*)d_in[2];   // 4096x4096
    const float* w2 = (const float*)d_in[3];   // 4096x1024
    const int nB = in_sizes[0];
    const int n1 = in_sizes[2];
    const int n2 = in_sizes[3];

    Partials* ws = (Partials*)d_ws;
    float* out = (float*)d_out;

    reduce_kernel<<<GRID, BLOCK, 0, stream>>>(p, y, w1, w2, nB / 4, n1 / 4, n2 / 4, ws);
    finalize_kernel<<<1, BLOCK, 0, stream>>>(ws, out, nB);
}

// Round 2
// 165.288 us; speedup vs baseline: 1.0254x; 1.0254x over previous
//
#include <hip/hip_runtime.h>
#include <hip/hip_bf16.h>

#define GRID  2048
#define BLOCK 256
#define LOG_CLAMP -100.0f

struct Partials {
    float bce[GRID];
    float w1s[GRID];
    float w2s[GRID];
    unsigned int cnt[GRID];
};

__device__ __forceinline__ float wave_reduce_f(float v) {
#pragma unroll
    for (int o = 32; o > 0; o >>= 1) v += __shfl_down(v, o, 64);
    return v;
}
__device__ __forceinline__ unsigned int wave_reduce_u(unsigned int v) {
#pragma unroll
    for (int o = 32; o > 0; o >>= 1) v += __shfl_down(v, o, 64);
    return v;
}
__device__ __forceinline__ double wave_reduce_d(double v) {
#pragma unroll
    for (int o = 32; o > 0; o >>= 1) v += __shfl_down(v, o, 64);
    return v;
}

// v_log_f32-based natural log: 2 VALU ops vs ~30 for libm logf.
// __logf(0) = -inf -> fmaxf clamps to -100, matching torch/jax semantics.
__device__ __forceinline__ float fast_ln(float x) {
    return __logf(x);
}

__global__ __launch_bounds__(BLOCK) void reduce_kernel(
    const float* __restrict__ p, const float* __restrict__ y,
    const float* __restrict__ w1, const float* __restrict__ w2,
    int nB4, int n14, int n24, Partials* __restrict__ ws)
{
    const float4* __restrict__ p4  = (const float4*)p;
    const float4* __restrict__ y4  = (const float4*)y;
    const float4* __restrict__ w14 = (const float4*)w1;
    const float4* __restrict__ w24 = (const float4*)w2;

    const int tid    = blockIdx.x * BLOCK + threadIdx.x;
    const int stride = GRID * BLOCK;

    float bce = 0.0f, s1 = 0.0f, s2 = 0.0f;
    unsigned int cnt = 0;

    // ---- BCE + accuracy over model_outputs / labels (4 iters/thread) ----
    for (int i = tid; i < nB4; i += stride) {
        float4 pv = p4[i];
        float4 yv = y4[i];
#define BCE_COMP(px, yx)                                                \
        {                                                               \
            float lp  = fmaxf(fast_ln(px), LOG_CLAMP);                  \
            float l1  = fmaxf(fast_ln(1.0f - (px)), LOG_CLAMP);         \
            /* y*lp + (1-y)*l1 == l1 + y*(lp - l1) */                   \
            bce += l1 + (yx) * (lp - l1);                               \
            cnt += (fabsf((px) - (yx)) < 0.5f) ? 1u : 0u;               \
        }
        BCE_COMP(pv.x, yv.x)
        BCE_COMP(pv.y, yv.y)
        BCE_COMP(pv.z, yv.z)
        BCE_COMP(pv.w, yv.w)
#undef BCE_COMP
    }

    // ---- sum of squares, w1 (8 iters/thread) ----
    for (int i = tid; i < n14; i += stride) {
        float4 v = w14[i];
        s1 += v.x * v.x + v.y * v.y + v.z * v.z + v.w * v.w;
    }

    // ---- sum of squares, w2 (2 iters/thread) ----
    for (int i = tid; i < n24; i += stride) {
        float4 v = w24[i];
        s2 += v.x * v.x + v.y * v.y + v.z * v.z + v.w * v.w;
    }

    // ---- block reduction: wave shuffle then LDS across 4 waves ----
    float rb = wave_reduce_f(bce);
    float r1 = wave_reduce_f(s1);
    float r2 = wave_reduce_f(s2);
    unsigned int rc = wave_reduce_u(cnt);

    __shared__ float sb[BLOCK / 64], s1s[BLOCK / 64], s2s[BLOCK / 64];
    __shared__ unsigned int scs[BLOCK / 64];
    const int wave = threadIdx.x >> 6;
    const int lane = threadIdx.x & 63;
    if (lane == 0) { sb[wave] = rb; s1s[wave] = r1; s2s[wave] = r2; scs[wave] = rc; }
    __syncthreads();
    if (threadIdx.x == 0) {
        float tb = 0.0f, t1 = 0.0f, t2 = 0.0f;
        unsigned int tc = 0;
#pragma unroll
        for (int w = 0; w < BLOCK / 64; ++w) { tb += sb[w]; t1 += s1s[w]; t2 += s2s[w]; tc += scs[w]; }
        ws->bce[blockIdx.x] = tb;
        ws->w1s[blockIdx.x] = t1;
        ws->w2s[blockIdx.x] = t2;
        ws->cnt[blockIdx.x] = tc;
    }
}

__global__ __launch_bounds__(BLOCK) void finalize_kernel(
    const Partials* __restrict__ ws, float* __restrict__ out, int nB)
{
    double bce = 0.0, s1 = 0.0, s2 = 0.0;
    unsigned int cnt = 0;
    for (int i = threadIdx.x; i < GRID; i += BLOCK) {
        bce += (double)ws->bce[i];
        s1  += (double)ws->w1s[i];
        s2  += (double)ws->w2s[i];
        cnt += ws->cnt[i];
    }
    double rb = wave_reduce_d(bce);
    double r1 = wave_reduce_d(s1);
    double r2 = wave_reduce_d(s2);
    unsigned int rc = wave_reduce_u(cnt);

    __shared__ double sb[BLOCK / 64], s1s[BLOCK / 64], s2s[BLOCK / 64];
    __shared__ unsigned int scs[BLOCK / 64];
    const int wave = threadIdx.x >> 6;
    const int lane = threadIdx.x & 63;
    if (lane == 0) { sb[wave] = rb; s1s[wave] = r1; s2s[wave] = r2; scs[wave] = rc; }
    __syncthreads();
    if (threadIdx.x == 0) {
        double tb = 0.0, t1 = 0.0, t2 = 0.0;
        unsigned int tc = 0;
#pragma unroll
        for (int w = 0; w < BLOCK / 64; ++w) { tb += sb[w]; t1 += s1s[w]; t2 += s2s[w]; tc += scs[w]; }
        const double invB = 1.0 / (double)nB;
        double result = -tb * invB + (0.01 * t1 + 0.001 * t2) * (0.5 * invB);
        out[0] = (float)result;
        out[1] = (float)tc;
    }
}

extern "C" void kernel_launch(void* const* d_in, const int* in_sizes, int n_in,
                              void* d_out, int out_size, void* d_ws, size_t ws_size,
                              hipStream_t stream) {
    const float* p  = (const float*)d_in[0];   // model_outputs
    const float* y  = (const float*)d_in[1];   // labels
    const float* w1 = (const float*)d_in[2];   // 4096x4096
    const float* w2 = (const float*)d_in[3];   // 4096x1024
    const int nB = in_sizes[0];
    const int n1 = in_sizes[2];
    const int n2 = in_sizes[3];

    Partials* ws = (Partials*)d_ws;
    float* out = (float*)d_out;

    reduce_kernel<<<GRID, BLOCK, 0, stream>>>(p, y, w1, w2, nB / 4, n1 / 4, n2 / 4, ws);
    finalize_kernel<<<1, BLOCK, 0, stream>>>(ws, out, nB);
}